// Round 6
// baseline (119.028 us; speedup 1.0000x reference)
//
#include <hip/hip_runtime.h>
#include <hip/hip_bf16.h>
#include <hip/hip_fp8.h>

// SNN forward, round 6: m201-geometry GEMM (256x256 tile, BK=64, 8 waves,
// 64 MFMA/wave/step, counted vmcnt), fragment-ordered LDS, permuted-coalesced
// fp8 epilogue. Recurrence uses permuted per-lane h-assignment.

#define B_    256
#define T_    250
#define NIN   700
#define NHID  512
#define NOUT  20
#define NSTEP 11          // K-steps of 64 (704 = 11*64, zero-padded)

typedef __attribute__((ext_vector_type(8))) short short8;
typedef __attribute__((ext_vector_type(4))) float f32x4;

static __device__ __forceinline__ ushort f2bf(float f) {
  union { float f; unsigned u; } v; v.f = f;
  unsigned r = (v.u + 0x7FFF + ((v.u >> 16) & 1)) >> 16;  // RNE
  return (ushort)r;
}
static __device__ __forceinline__ unsigned cvtpk_bf16(float a, float b) {
  unsigned r;
  asm("v_cvt_pk_bf16_f32 %0, %1, %2" : "=v"(r) : "v"(a), "v"(b));
  return r;
}
static __device__ __forceinline__ void gload_lds16(const void* g, void* l) {
  __builtin_amdgcn_global_load_lds(
      (const __attribute__((address_space(1))) unsigned*)g,
      (__attribute__((address_space(3))) unsigned*)l, 16, 0, 0);
}
// storage permutation within a 512-col row (self-inverse):
static __device__ __forceinline__ int hperm(int s) {
  return (s & 256) | ((s & 15) << 4) | ((s >> 4) & 15);
}

// ---------------- prep: w1 -> bf16 fragment slabs ----------------
// elem = ((nh*NSTEP+kt)<<14) + (k32<<13) + (cb<<9) + (lane<<3) + e
// col = nh*256 + cb*16 + (lane&15); k = kt*64 + k32*32 + (lane>>4)*8 + e
__global__ __launch_bounds__(256) void prep_kernel(
    const float* __restrict__ w1, ushort* __restrict__ w1frag) {
  int i = blockIdx.x * 256 + threadIdx.x;
  if (i >= 2 * NSTEP * 16384) return;
  int e    = i & 7;
  int lane = (i >> 3) & 63;
  int cb   = (i >> 9) & 15;
  int k32  = (i >> 13) & 1;
  int slab = i >> 14;
  int nh = slab / NSTEP, kt = slab - nh * NSTEP;
  int col = nh * 256 + cb * 16 + (lane & 15);
  int k   = kt * 64 + k32 * 32 + (lane >> 4) * 8 + e;
  w1frag[i] = (k < NIN) ? f2bf(w1[(size_t)col * NIN + k]) : (ushort)0;
}

// ---------------- MFMA GEMM ----------------
// grid = 512; block = 512 (8 waves, 2x4), tile 256 rows x 256 cols, BK=64.
// p -> (tl = (p>>4)*8 + (p&7), nh = (p>>3)&1): n-halves of a t share an XCD.
__global__ __launch_bounds__(512, 2) void gemm_mfma(
    const float* __restrict__ x, const ushort* __restrict__ w1frag,
    const float* __restrict__ alpha, unsigned char* __restrict__ iff,
    int t0, int tcount) {
  __shared__ __align__(16) char Al[2][32768];
  __shared__ __align__(16) char Bl[2][32768];

  int p = blockIdx.x;
  int tl = ((p >> 4) << 3) | (p & 7);
  int nh = (p >> 3) & 1;
  if (tl >= tcount) return;
  int t = t0 + tl;

  int tid = threadIdx.x, lane = tid & 63, wave = tid >> 6;
  int wr = wave >> 2, wc = wave & 3;       // 2 x 4 wave grid
  int lm = lane & 15, lk = lane >> 4;

  // A staging: thread -> (row=tid>>1, oct-quad so4)
  int srow = tid >> 1;
  int so4  = (tid & 1) * 4;
  const float* ap = x + ((size_t)srow * T_ + t) * NIN;

  f32x4 acc[8][4];
#pragma unroll
  for (int i = 0; i < 8; ++i)
#pragma unroll
    for (int j = 0; j < 4; ++j) acc[i][j] = (f32x4){0.f, 0.f, 0.f, 0.f};

  float4 sa[8];

#define LOADA(KT) do { _Pragma("unroll")                                     \
  for (int q_ = 0; q_ < 4; ++q_) {                                           \
    int k0_ = (KT) * 64 + so4 * 8 + q_ * 8;                                  \
    sa[2*q_]   = (k0_ + 4 <= NIN) ? *(const float4*)(ap + k0_)               \
                                  : (float4){0.f,0.f,0.f,0.f};               \
    sa[2*q_+1] = (k0_ + 8 <= NIN) ? *(const float4*)(ap + k0_ + 4)           \
                                  : (float4){0.f,0.f,0.f,0.f};               \
  } } while (0)

#define WRITEA(BUF) do { _Pragma("unroll")                                   \
  for (int q_ = 0; q_ < 4; ++q_) {                                           \
    int o_ = so4 + q_;                                                       \
    int byo_ = (((o_ >> 2) * 16 + (srow >> 4)) << 10)                        \
             + (((((o_ & 3) << 4) | (srow & 15))) << 4);                     \
    byo_ ^= ((srow >> 4) & 7) << 4;                                          \
    uint4 pk_;                                                               \
    pk_.x = cvtpk_bf16(sa[2*q_].x,   sa[2*q_].y);                            \
    pk_.y = cvtpk_bf16(sa[2*q_].z,   sa[2*q_].w);                            \
    pk_.z = cvtpk_bf16(sa[2*q_+1].x, sa[2*q_+1].y);                          \
    pk_.w = cvtpk_bf16(sa[2*q_+1].z, sa[2*q_+1].w);                          \
    *(uint4*)(&Al[BUF][byo_]) = pk_;                                         \
  } } while (0)

#define STAGEB(BUF, KT) do {                                                 \
    const char* gs_ = (const char*)w1frag                                    \
                    + (((size_t)(nh * NSTEP + (KT))) << 15);                 \
    _Pragma("unroll")                                                        \
    for (int i_ = 0; i_ < 4; ++i_) {                                         \
      int off_ = i_ * 8192 + wave * 1024;                                    \
      gload_lds16(gs_ + off_ + lane * 16, &Bl[BUF][off_]);                   \
    } } while (0)

#define COMPUTE(BUF) do { _Pragma("unroll")                                  \
  for (int h_ = 0; h_ < 2; ++h_) {                                           \
    short8 af_[8], bf_[4];                                                   \
    _Pragma("unroll")                                                        \
    for (int i_ = 0; i_ < 8; ++i_)                                           \
      af_[i_] = *(const short8*)(&Al[BUF][((h_ * 16 + wr * 8 + i_) << 10)    \
                                          + ((lane * 16) ^ (i_ << 4))]);     \
    _Pragma("unroll")                                                        \
    for (int j_ = 0; j_ < 4; ++j_)                                           \
      bf_[j_] = *(const short8*)(&Bl[BUF][((h_ * 16 + wc * 4 + j_) << 10)    \
                                          + lane * 16]);                     \
    __builtin_amdgcn_s_setprio(1);                                           \
    _Pragma("unroll")                                                        \
    for (int i_ = 0; i_ < 8; ++i_)                                           \
      _Pragma("unroll")                                                      \
      for (int j_ = 0; j_ < 4; ++j_)                                         \
        acc[i_][j_] = __builtin_amdgcn_mfma_f32_16x16x32_bf16(               \
            af_[i_], bf_[j_], acc[i_][j_], 0, 0, 0);                         \
    __builtin_amdgcn_s_setprio(0);                                           \
  } } while (0)

  // prologue
  LOADA(0);
  STAGEB(0, 0);
  WRITEA(0);                 // compiler waits the 8 A-loads; B's 4 stay out
  LOADA(1);
  asm volatile("s_waitcnt vmcnt(8) lgkmcnt(0)" ::: "memory");  // drain B(0)
  __builtin_amdgcn_s_barrier();
  __builtin_amdgcn_sched_barrier(0);

#pragma unroll 2
  for (int kt = 0; kt < NSTEP; ++kt) {
    const int cur = kt & 1, nxt = cur ^ 1;
    if (kt + 1 < NSTEP) STAGEB(nxt, kt + 1);   // 4 vm, in flight across MFMA
    COMPUTE(cur);
    if (kt + 1 < NSTEP) {
      WRITEA(nxt);                             // waits only the 8 A-loads
      if (kt + 2 < NSTEP) {
        LOADA(kt + 2);                         // 8 vm stay in flight
        asm volatile("s_waitcnt vmcnt(8) lgkmcnt(0)" ::: "memory");
      } else {
        asm volatile("s_waitcnt vmcnt(0) lgkmcnt(0)" ::: "memory");
      }
      __builtin_amdgcn_s_barrier();
      __builtin_amdgcn_sched_barrier(0);
    }
  }
#undef LOADA
#undef WRITEA
#undef STAGEB
#undef COMPUTE

  // epilogue: scale by (1-alpha[col]); pack 4 fp8 (j=0..3) -> one u32 at the
  // permuted position s = lm*16 + wc*4  (col = cb*16+lm <-> s = lm*16+cb).
  float scl[4];
#pragma unroll
  for (int j = 0; j < 4; ++j)
    scl[j] = 1.0f - alpha[nh * 256 + wc * 64 + j * 16 + lm];
#pragma unroll
  for (int i = 0; i < 8; ++i) {
#pragma unroll
    for (int r = 0; r < 4; ++r) {
      int row = wr * 128 + i * 16 + lk * 4 + r;   // batch index b
      unsigned u = 0;
#pragma unroll
      for (int j = 0; j < 4; ++j) {
        __hip_fp8_e4m3 q(acc[i][j][r] * scl[j]);
        u |= ((unsigned)q.__x) << (8 * j);
      }
      *(unsigned*)(iff + ((size_t)(tl * 256 + row)) * NHID
                   + nh * 256 + lm * 16 + wc * 4) = u;
    }
  }
}

// ---------------- fused recurrence ----------------
// 256 blocks x 64 threads; block b = batch row. Lane owns the 8 units whose
// STORAGE bytes are [lane*8, lane*8+8); actual h = hperm(lane*8+r).
// iff pre-scaled by (1-alpha). Fast path while no spike has ever fired.
__global__ __launch_bounds__(64) void snn_recur(
    const unsigned char* __restrict__ iff, const float* __restrict__ wrec,
    const float* __restrict__ wout,
    const float* __restrict__ alpha, const float* __restrict__ rho,
    const float* __restrict__ beta_a, const float* __restrict__ beta_out,
    float* __restrict__ state, int* __restrict__ flags,
    float* __restrict__ dout, int Tc, int first, int last) {
  int lane = threadIdx.x;
  int b = blockIdx.x;
  int hbase = lane * 8;

  float* v1s = state;
  float* a1s = state + B_ * NHID;
  float* sps = state + 2 * B_ * NHID;
  float* vos = state + 3 * B_ * NHID;
  float* oss = vos + B_ * NOUT;

  int hact[8];
#pragma unroll
  for (int r = 0; r < 8; ++r) hact[r] = hperm(hbase + r);

  float v1[8], a1[8], sp[8], al[8], rh[8], ba[8];
#pragma unroll
  for (int r = 0; r < 8; ++r) {
    int h = hact[r];
    al[r] = alpha[h]; rh[r] = rho[h]; ba[r] = beta_a[h];
    if (first) { v1[r] = 0.f; a1[r] = 0.f; sp[r] = 0.f; }
    else {   // state kept in storage (permuted) order
      v1[r] = v1s[(size_t)b * NHID + hbase + r];
      a1[r] = a1s[(size_t)b * NHID + hbase + r];
      sp[r] = sps[(size_t)b * NHID + hbase + r];
    }
  }
  float vout = 0.f, osum = 0.f, bo = 0.f;
  if (lane < NOUT) {
    bo = beta_out[lane];
    if (!first) { vout = vos[b * NOUT + lane]; osum = oss[b * NOUT + lane]; }
  }

  int mode = first ? 0 : flags[b];
  int tle = 0;

  if (mode == 0) {
    // fast path: no spike has ever fired
    uint2 pf[8];
#pragma unroll
    for (int j = 0; j < 8; ++j) {
      int tl = (j < Tc) ? j : (Tc - 1);
      pf[j] = *(const uint2*)(iff + ((size_t)tl * B_ + b) * NHID + hbase);
    }
    bool esc = false;
    for (int tb = 0; tb < Tc && !esc; tb += 8) {
#pragma unroll
      for (int j = 0; j < 8; ++j) {
        int tl = tb + j;
        if (!esc && tl < Tc) {
          float tv[8];
#pragma unroll
          for (int r = 0; r < 8; ++r) {
            unsigned w = (r < 4) ? pf[j].x : pf[j].y;
            __hip_fp8_e4m3 q; q.__x = (unsigned char)((w >> ((r & 3) * 8)) & 255u);
            tv[r] = al[r] * v1[r] + (float)q;   // iff pre-scaled by (1-alpha)
          }
          float m01 = fmaxf(tv[0], tv[1]), m23 = fmaxf(tv[2], tv[3]);
          float m45 = fmaxf(tv[4], tv[5]), m67 = fmaxf(tv[6], tv[7]);
          float mx = fmaxf(fmaxf(m01, m23), fmaxf(m45, m67));
          if (__ballot(mx > 1.0f)) {
            esc = true; tle = tl;   // redo step tl in full mode
          } else {
#pragma unroll
            for (int r = 0; r < 8; ++r) v1[r] = tv[r];
            int nt = (tl + 8 < Tc) ? (tl + 8) : (Tc - 1);
            pf[j] = *(const uint2*)(iff + ((size_t)nt * B_ + b) * NHID + hbase);
          }
        }
      }
    }
    if (!esc) tle = Tc;
    mode = esc ? 1 : 0;
  }

  // full path (fallback / post-first-spike)
  unsigned long long mask[8];
#pragma unroll
  for (int r = 0; r < 8; ++r) mask[r] = __ballot(sp[r] != 0.f);

  for (int tl = tle; tl < Tc; ++tl) {
    uint2 w2 = *(const uint2*)(iff + ((size_t)tl * B_ + b) * NHID + hbase);
    float iv[8];
#pragma unroll
    for (int r = 0; r < 8; ++r) {
      unsigned w = (r < 4) ? w2.x : w2.y;
      __hip_fp8_e4m3 q; q.__x = (unsigned char)((w >> ((r & 3) * 8)) & 255u);
      iv[r] = (float)q;   // = (1-alpha)*i_ff
    }
    unsigned long long anyp = mask[0] | mask[1] | mask[2] | mask[3] |
                              mask[4] | mask[5] | mask[6] | mask[7];
    if (anyp) {
      float rec[8] = {0.f,0.f,0.f,0.f,0.f,0.f,0.f,0.f};
#pragma unroll
      for (int r2 = 0; r2 < 8; ++r2) {
        unsigned long long mm = mask[r2];
        while (mm) {
          int l2 = __ffsll(mm) - 1; mm &= (mm - 1);
          int hp = hperm(l2 * 8 + r2);
#pragma unroll
          for (int r = 0; r < 8; ++r)
            rec[r] += wrec[(size_t)hact[r] * NHID + hp];
        }
      }
#pragma unroll
      for (int r = 0; r < 8; ++r) iv[r] += (1.0f - al[r]) * rec[r];
    }

    float s[8];
#pragma unroll
    for (int r = 0; r < 8; ++r) {
      a1[r] = rh[r] * a1[r] + ba[r] * sp[r];
      v1[r] = al[r] * v1[r] + iv[r] - a1[r];
      s[r] = (v1[r] - 1.0f > 0.0f) ? 1.0f : 0.0f;
      v1[r] -= s[r];
      sp[r] = s[r];
      mask[r] = __ballot(s[r] != 0.f);
    }

    unsigned long long anyc = mask[0] | mask[1] | mask[2] | mask[3] |
                              mask[4] | mask[5] | mask[6] | mask[7];
    if (lane < NOUT) {
      float io = 0.f;
      if (anyc) {
#pragma unroll
        for (int r2 = 0; r2 < 8; ++r2) {
          unsigned long long mm = mask[r2];
          while (mm) {
            int l2 = __ffsll(mm) - 1; mm &= (mm - 1);
            int hp = hperm(l2 * 8 + r2);
            io += wout[(size_t)lane * NHID + hp];
          }
        }
      }
      vout = bo * vout + (1.0f - bo) * io;
      float so = (vout - 1.0f > 0.0f) ? 1.0f : 0.0f;
      vout -= so;
      osum += vout;
    }
  }

  if (last) {
    if (lane < NOUT) dout[b * NOUT + lane] = osum / (float)T_;
  } else {
#pragma unroll
    for (int r = 0; r < 8; ++r) {
      v1s[(size_t)b * NHID + hbase + r] = v1[r];
      a1s[(size_t)b * NHID + hbase + r] = a1[r];
      sps[(size_t)b * NHID + hbase + r] = sp[r];
    }
    if (lane < NOUT) { vos[b * NOUT + lane] = vout; oss[b * NOUT + lane] = osum; }
    if (lane == 0) flags[b] = mode;
  }
}

extern "C" void kernel_launch(void* const* d_in, const int* in_sizes, int n_in,
                              void* d_out, int out_size, void* d_ws, size_t ws_size,
                              hipStream_t stream) {
  const float* x      = (const float*)d_in[0];
  const float* w1     = (const float*)d_in[1];
  const float* wrec   = (const float*)d_in[2];
  const float* wout   = (const float*)d_in[3];
  const float* alpha  = (const float*)d_in[4];
  const float* rho    = (const float*)d_in[5];
  const float* beta_a = (const float*)d_in[6];
  const float* bout   = (const float*)d_in[7];
  float* out = (float*)d_out;

  char* ws = (char*)d_ws;
  const size_t w1frag_bytes = (size_t)2 * NSTEP * 16384 * 2;                 // 704 KB
  const size_t state_off = w1frag_bytes;
  const size_t state_bytes = (size_t)(3 * B_ * NHID + 2 * B_ * NOUT) * 4;
  const size_t flags_off = state_off + state_bytes;
  const size_t iff_off   = flags_off + B_ * 4;

  ushort* w1frag = (ushort*)(ws);
  float*  statep = (float*)(ws + state_off);
  int*    flagsp = (int*)(ws + flags_off);
  unsigned char* iff = (unsigned char*)(ws + iff_off);

  const size_t per_step = (size_t)B_ * NHID;  // 128 KB per timestep (fp8)
  long long avail = (long long)ws_size - (long long)iff_off;
  int Tc = (int)(avail / (long long)per_step);
  if (Tc > T_) Tc = T_;
  if (Tc < 1) Tc = 1;

  prep_kernel<<<dim3((2 * NSTEP * 16384 + 255) / 256), dim3(256), 0, stream>>>(
      w1, w1frag);

  for (int t0 = 0; t0 < T_; t0 += Tc) {
    int tc = (T_ - t0 < Tc) ? (T_ - t0) : Tc;
    gemm_mfma<<<dim3(512), dim3(512), 0, stream>>>(x, w1frag, alpha, iff, t0, tc);
    snn_recur<<<dim3(B_), dim3(64), 0, stream>>>(
        iff, wrec, wout, alpha, rho, beta_a, bout, statep, flagsp, out,
        tc, (t0 == 0) ? 1 : 0, (t0 + tc >= T_) ? 1 : 0);
  }
}